// Round 4
// baseline (26824.414 us; speedup 1.0000x reference)
//
#include <hip/hip_runtime.h>
#include <hip/hip_bf16.h>

// ---------------------------------------------------------------------------
// RSSMCore persistent-scan v3.
// R3 lesson: split-K partials round-tripped through the coherent (sc0sc1)
// path at 8B granularity = 7.5 GB at ~456 GB/s = the whole 17 ms. Fix:
// minimal split-K (gi x2, gh x4 spread over idle phase slots, x2 x4, pp x1),
// outputs via normal cached stores, pp GEMM fused with categorical sampling
// (32-col tile = one softmax group), prefetch in phase GEMMs.
// 6 phases/step:  A gather->xe | B gi + gh(t)q3 | C gates->h | D x2 + gh(t+1)q0
//                 E x2e-LN + gh(t+1)q1 | F pp+sample + gh(t+1)q2
// ---------------------------------------------------------------------------

#define BK 32
#define LDP 66
#define NBLK 512

enum { TR_NONE = 0, TR_SCALEROW = 1, TR_LNELU = 2 };

// ---------------- coherent (L2-bypassing) access helpers -------------------
__device__ inline float cload(const float* p) {
  return __hip_atomic_load(p, __ATOMIC_RELAXED, __HIP_MEMORY_SCOPE_SYSTEM);
}
__device__ inline void cstore(float* p, float v) {
  __hip_atomic_store(p, v, __ATOMIC_RELAXED, __HIP_MEMORY_SCOPE_SYSTEM);
}
__device__ inline float2 cload2(const float* p) {
  unsigned long long u = __hip_atomic_load((const unsigned long long*)p,
                                           __ATOMIC_RELAXED, __HIP_MEMORY_SCOPE_SYSTEM);
  float2 r;
  r.x = __uint_as_float((unsigned)u);
  r.y = __uint_as_float((unsigned)(u >> 32));
  return r;
}
__device__ inline void cstore2(float* p, float x, float y) {
  unsigned long long u =
      ((unsigned long long)__float_as_uint(y) << 32) | (unsigned long long)__float_as_uint(x);
  __hip_atomic_store((unsigned long long*)p, u, __ATOMIC_RELAXED, __HIP_MEMORY_SCOPE_SYSTEM);
}
__device__ inline int cloadi(const int* p) {
  return __hip_atomic_load(p, __ATOMIC_RELAXED, __HIP_MEMORY_SCOPE_SYSTEM);
}
__device__ inline void cstorei(int* p, int v) {
  __hip_atomic_store(p, v, __ATOMIC_RELAXED, __HIP_MEMORY_SCOPE_SYSTEM);
}

// XLA f32 tanh rational approximation (mul/add, no contraction) -------------
__device__ inline float xla_tanh(float x) {
  float ax = fabsf(x);
  float xc = fminf(fmaxf(x, -7.90531110763549805f), 7.90531110763549805f);
  float x2 = __fmul_rn(xc, xc);
  float p = -2.76076847742355e-16f;
  p = __fadd_rn(__fmul_rn(p, x2), 2.00018790482477e-13f);
  p = __fadd_rn(__fmul_rn(p, x2), -8.60467152213735e-11f);
  p = __fadd_rn(__fmul_rn(p, x2), 5.12229709037114e-08f);
  p = __fadd_rn(__fmul_rn(p, x2), 1.48572235717979e-05f);
  p = __fadd_rn(__fmul_rn(p, x2), 6.37261928875436e-04f);
  p = __fadd_rn(__fmul_rn(p, x2), 4.89352455891786e-03f);
  float num = __fmul_rn(xc, p);
  float q = 1.19825839466702e-06f;
  q = __fadd_rn(__fmul_rn(q, x2), 1.18534705686654e-04f);
  q = __fadd_rn(__fmul_rn(q, x2), 2.26843463243900e-03f);
  q = __fadd_rn(__fmul_rn(q, x2), 4.89352518554385e-03f);
  float r = __fdiv_rn(num, q);
  return ax < 0.0004f ? x : r;
}

__device__ inline float sigm(float x) { return 1.0f / (1.0f + expf(-x)); }

// Threefry2x32 (20 rounds), matches jax/_src/prng.py ------------------------
__device__ inline void tfround(unsigned& x0, unsigned& x1, int r) {
  x0 += x1; x1 = (x1 << r) | (x1 >> (32 - r)); x1 ^= x0;
}
__device__ inline uint2 threefry(unsigned k0, unsigned k1, unsigned c0, unsigned c1) {
  unsigned ks2 = k0 ^ k1 ^ 0x1BD11BDAu;
  unsigned x0 = c0 + k0, x1 = c1 + k1;
  tfround(x0, x1, 13); tfround(x0, x1, 15); tfround(x0, x1, 26); tfround(x0, x1, 6);
  x0 += k1; x1 += ks2 + 1u;
  tfround(x0, x1, 17); tfround(x0, x1, 29); tfround(x0, x1, 16); tfround(x0, x1, 24);
  x0 += ks2; x1 += k0 + 2u;
  tfround(x0, x1, 13); tfround(x0, x1, 15); tfround(x0, x1, 26); tfround(x0, x1, 6);
  x0 += k0; x1 += k1 + 3u;
  tfround(x0, x1, 17); tfround(x0, x1, 29); tfround(x0, x1, 16); tfround(x0, x1, 24);
  x0 += k1; x1 += ks2 + 4u;
  tfround(x0, x1, 13); tfround(x0, x1, 15); tfround(x0, x1, 26); tfround(x0, x1, 6);
  x0 += ks2; x1 += k0 + 5u;
  return make_uint2(x0, x1);
}

// ======================= round-1 proven tiled GEMM (pre/post) ==============
struct GemmArgs {
  const float* A; int lda; const float* B; int ldb; int K; int ksplit;
  const float* A2; int lda2; const float* B2; int ldb2; int K2;
  int N; const float* bias;
  const float* t1s; const float* t1g; const float* t1b;
  float* C; int ldc; long partStride;
};

template <int TRA>
__device__ void gemm_tiles(float acc[4][4], float (*As)[LDP], float (*Bs)[LDP],
                           const float* A, int lda, const float* B, int ldb,
                           int kB, int kE, int mBase, int cBase, int N,
                           const float* s0, const float* g0, const float* b0) {
  const int tid = threadIdx.x;
  const int ar = tid >> 2;
  const int ak = (tid & 3) << 3;
  const int bk = tid >> 3;
  const int bc = (tid & 7) << 3;
  const int r0 = (tid >> 4) << 2;
  const int c0 = (tid & 15) << 2;

  float rowS = 1.f, rowM = 0.f, rowR = 1.f;
  if (TRA == TR_SCALEROW) rowS = s0[mBase + ar];
  else if (TRA == TR_LNELU) {
    rowM = s0[(mBase + ar) * 2];
    rowR = s0[(mBase + ar) * 2 + 1];
  }

  for (int kb = kB; kb < kE; kb += BK) {
    {
      const float* Ap = A + (long)(mBase + ar) * lda + kb + ak;
      float v[8];
      if (kb + ak + 7 < kE) {
        float4 u0 = *(const float4*)(Ap);
        float4 u1 = *(const float4*)(Ap + 4);
        v[0] = u0.x; v[1] = u0.y; v[2] = u0.z; v[3] = u0.w;
        v[4] = u1.x; v[5] = u1.y; v[6] = u1.z; v[7] = u1.w;
      } else {
#pragma unroll
        for (int i = 0; i < 8; i++) v[i] = (kb + ak + i < kE) ? Ap[i] : 0.f;
      }
#pragma unroll
      for (int i = 0; i < 8; i++) {
        int k = kb + ak + i;
        float x = 0.f;
        if (k < kE) {
          x = v[i];
          if (TRA == TR_SCALEROW) {
            x *= rowS;
          } else if (TRA == TR_LNELU) {
            x = (x - rowM) * rowR * g0[k] + b0[k];
            x = x > 0.f ? x : expm1f(x);
          }
        }
        As[ak + i][ar] = x;
      }
    }
    {
      int k = kb + bk;
      const float* Bp = B + (long)k * ldb + cBase + bc;
      if (k < kE && cBase + bc + 7 < N) {
        float4 u0 = *(const float4*)(Bp);
        float4 u1 = *(const float4*)(Bp + 4);
        Bs[bk][bc + 0] = u0.x; Bs[bk][bc + 1] = u0.y;
        Bs[bk][bc + 2] = u0.z; Bs[bk][bc + 3] = u0.w;
        Bs[bk][bc + 4] = u1.x; Bs[bk][bc + 5] = u1.y;
        Bs[bk][bc + 6] = u1.z; Bs[bk][bc + 7] = u1.w;
      } else {
#pragma unroll
        for (int i = 0; i < 8; i++)
          Bs[bk][bc + i] = (k < kE && cBase + bc + i < N) ? Bp[i] : 0.f;
      }
    }
    __syncthreads();
#pragma unroll
    for (int kk = 0; kk < BK; kk++) {
      float4 a4 = *(const float4*)&As[kk][r0];
      float4 b4 = *(const float4*)&Bs[kk][c0];
      float av[4] = {a4.x, a4.y, a4.z, a4.w};
      float bv[4] = {b4.x, b4.y, b4.z, b4.w};
#pragma unroll
      for (int i = 0; i < 4; i++)
#pragma unroll
        for (int j = 0; j < 4; j++) acc[i][j] += av[i] * bv[j];
    }
    __syncthreads();
  }
}

template <int TRA, int TRA2>
__global__ __launch_bounds__(256) void k_gemm(GemmArgs g) {
  __shared__ float As[BK][LDP];
  __shared__ float Bs[BK][LDP];
  const int nT = blockIdx.x, ks = blockIdx.y, mT = blockIdx.z;
  const int mBase = mT * 64, cBase = nT * 64;
  float acc[4][4] = {};
  int chunk = (((g.K + g.ksplit - 1) / g.ksplit) + 31) & ~31;
  int kB = ks * chunk, kE = min(g.K, kB + chunk);
  if (kB < kE)
    gemm_tiles<TRA>(acc, As, Bs, g.A, g.lda, g.B, g.ldb, kB, kE, mBase, cBase,
                    g.N, g.t1s, g.t1g, g.t1b);
  if (g.A2) {
    int chunk2 = (((g.K2 + g.ksplit - 1) / g.ksplit) + 31) & ~31;
    int kB2 = ks * chunk2, kE2 = min(g.K2, kB2 + chunk2);
    if (kB2 < kE2)
      gemm_tiles<TRA2>(acc, As, Bs, g.A2, g.lda2, g.B2, g.ldb2, kB2, kE2, mBase,
                       cBase, g.N, nullptr, nullptr, nullptr);
  }
  const int tid = threadIdx.x;
  const int r0 = (tid >> 4) << 2, c0 = (tid & 15) << 2;
  float* Cb = g.C + (long)ks * g.partStride;
#pragma unroll
  for (int i = 0; i < 4; i++) {
    float4 v = make_float4(acc[i][0], acc[i][1], acc[i][2], acc[i][3]);
    if (ks == 0 && g.bias) {
      int c = cBase + c0;
      v.x += (c + 0 < g.N) ? g.bias[c + 0] : 0.f;
      v.y += (c + 1 < g.N) ? g.bias[c + 1] : 0.f;
      v.z += (c + 2 < g.N) ? g.bias[c + 2] : 0.f;
      v.w += (c + 3 < g.N) ? g.bias[c + 3] : 0.f;
    }
    *(float4*)&Cb[(long)(mBase + r0 + i) * g.ldc + cBase + c0] = v;
  }
}

__global__ __launch_bounds__(256) void k_prstat(const float* xp, float* stats, int N) {
  int wave = threadIdx.x >> 6, lane = threadIdx.x & 63;
  int r = blockIdx.x * 4 + wave;
  float s = 0.f, sq = 0.f;
  for (int c = lane; c < N; c += 64) {
    float v = xp[(long)r * 1024 + c];
    s += v; sq += v * v;
  }
#pragma unroll
  for (int off = 32; off >= 1; off >>= 1) {
    s += __shfl_down(s, off);
    sq += __shfl_down(sq, off);
  }
  if (lane == 0) {
    float mean = s / N, var = sq / N - mean * mean;
    stats[r * 2] = mean;
    stats[r * 2 + 1] = 1.0f / sqrtf(var + 1e-3f);
  }
}

// ======================= persistent scan kernel ============================
struct ScanArgs {
  const float* h0;
  const float* zw; const float* gwi; const float* gwh;
  const float* gbi; const float* gbh;
  const float* ph_w; const float* pp_w; const float* pp_b;
  const float* in_g; const float* in_b; const float* po_g; const float* po_b;
  const float* mask;
  const float* xa_base; const float* x2_base; const float* xa_t0;
  float* gi_p;   // 2 x [64][6144]
  float* gh_p;   // 4 x [64][6144]
  float* x2_p;   // 4 x [64][1024]
  float* xe; float* x2e; int* idx;
  float* posts; float* samples; float* feats; float* hlast; float* zlast;
  unsigned* bar;
};

// Relaxed-only two-level grid barrier (proven R3). No fences/acquires —
// visibility via sc0sc1 data accesses + vmcnt(0) before arrival.
__device__ inline void gridbar(unsigned* bar, unsigned& lgen) {
  asm volatile("s_waitcnt vmcnt(0)" ::: "memory");
  __syncthreads();
  lgen++;
  if (threadIdx.x == 0) {
    int cell = (blockIdx.x & 7) * 32;
    unsigned prev = __hip_atomic_fetch_add(&bar[cell], 1u, __ATOMIC_RELAXED,
                                           __HIP_MEMORY_SCOPE_AGENT);
    if (prev == (unsigned)(NBLK / 8) * lgen - 1u) {
      unsigned p2 = __hip_atomic_fetch_add(&bar[256], 1u, __ATOMIC_RELAXED,
                                           __HIP_MEMORY_SCOPE_AGENT);
      if (p2 == 8u * lgen - 1u)
        __hip_atomic_store(&bar[288], lgen, __ATOMIC_RELAXED,
                           __HIP_MEMORY_SCOPE_AGENT);
    }
    while (__hip_atomic_load(&bar[288], __ATOMIC_RELAXED,
                             __HIP_MEMORY_SCOPE_AGENT) < lgen)
      __builtin_amdgcn_s_sleep(8);
  }
  __syncthreads();
}

// 64x64 tile GEMM with k-prefetch. A coherent, B cached, C coherent.
template <int TRA>
__device__ void phase_gemm(float (*As)[LDP], float (*Bs)[LDP],
                           const float* A, int lda, const float* B, int ldb,
                           int kB, int kE, int cBase, int N,
                           const float* rowScale, float* C, int ldc,
                           const float* baseAdd, const float* colBias) {
  const int tid = threadIdx.x;
  const int ar = tid >> 2, ak = (tid & 3) << 3;
  const int bk = tid >> 3, bc = (tid & 7) << 3;
  const int r0 = (tid >> 4) << 2, c0 = (tid & 15) << 2;
  float acc[4][4] = {};
  float rowS = (TRA == TR_SCALEROW) ? rowScale[ar] : 1.f;
  float v[8], w[8];

  auto ldA = [&](int kb) {
    const float* Ap = A + (long)ar * lda + kb + ak;
    if (kb + ak + 7 < kE) {
#pragma unroll
      for (int i = 0; i < 4; i++) {
        float2 u = cload2(Ap + 2 * i);
        v[2 * i] = u.x; v[2 * i + 1] = u.y;
      }
    } else {
#pragma unroll
      for (int i = 0; i < 8; i++) v[i] = (kb + ak + i < kE) ? cload(Ap + i) : 0.f;
    }
  };
  auto ldB = [&](int kb) {
    int k = kb + bk;
    const float* Bp = B + (long)k * ldb + cBase + bc;
    if (k < kE && cBase + bc + 7 < N) {
      float4 u0 = *(const float4*)(Bp);
      float4 u1 = *(const float4*)(Bp + 4);
      w[0] = u0.x; w[1] = u0.y; w[2] = u0.z; w[3] = u0.w;
      w[4] = u1.x; w[5] = u1.y; w[6] = u1.z; w[7] = u1.w;
    } else {
#pragma unroll
      for (int i = 0; i < 8; i++)
        w[i] = (k < kE && cBase + bc + i < N) ? Bp[i] : 0.f;
    }
  };

  ldA(kB); ldB(kB);
  for (int kb = kB; kb < kE; kb += BK) {
#pragma unroll
    for (int i = 0; i < 8; i++)
      As[ak + i][ar] = (TRA == TR_SCALEROW) ? v[i] * rowS : v[i];
#pragma unroll
    for (int i = 0; i < 8; i++) Bs[bk][bc + i] = w[i];
    __syncthreads();
    if (kb + BK < kE) { ldA(kb + BK); ldB(kb + BK); }
#pragma unroll
    for (int kk = 0; kk < BK; kk++) {
      float4 a4 = *(const float4*)&As[kk][r0];
      float4 b4 = *(const float4*)&Bs[kk][c0];
      float av[4] = {a4.x, a4.y, a4.z, a4.w};
      float bv[4] = {b4.x, b4.y, b4.z, b4.w};
#pragma unroll
      for (int i = 0; i < 4; i++)
#pragma unroll
        for (int j = 0; j < 4; j++) acc[i][j] += av[i] * bv[j];
    }
    __syncthreads();
  }

#pragma unroll
  for (int i = 0; i < 4; i++) {
    float4 v4 = make_float4(acc[i][0], acc[i][1], acc[i][2], acc[i][3]);
    int c = cBase + c0;
    if (baseAdd) {
      const float* bp = baseAdd + (long)(r0 + i) * 1024 + c;
      v4.x += (c + 0 < N) ? bp[0] : 0.f;
      v4.y += (c + 1 < N) ? bp[1] : 0.f;
      v4.z += (c + 2 < N) ? bp[2] : 0.f;
      v4.w += (c + 3 < N) ? bp[3] : 0.f;
    }
    if (colBias) {
      v4.x += (c + 0 < N) ? colBias[c + 0] : 0.f;
      v4.y += (c + 1 < N) ? colBias[c + 1] : 0.f;
      v4.z += (c + 2 < N) ? colBias[c + 2] : 0.f;
      v4.w += (c + 3 < N) ? colBias[c + 3] : 0.f;
    }
    float* Cp = &C[(long)(r0 + i) * ldc + cBase + c0];
    cstore2(Cp, v4.x, v4.y);
    cstore2(Cp + 2, v4.z, v4.w);
  }
}

// Block-wide LN helper
__device__ inline void ln_reduce(float s, float sq, float* red, float& mean,
                                 float& rstd) {
  const int tid = threadIdx.x;
#pragma unroll
  for (int off = 32; off >= 1; off >>= 1) {
    s += __shfl_down(s, off);
    sq += __shfl_down(sq, off);
  }
  if ((tid & 63) == 0) { red[tid >> 6] = s; red[4 + (tid >> 6)] = sq; }
  __syncthreads();
  if (tid == 0) {
    float S = red[0] + red[1] + red[2] + red[3];
    float Q = red[4] + red[5] + red[6] + red[7];
    float m = S / 1000.f;
    float var = Q / 1000.f - m * m;
    red[8] = m;
    red[9] = 1.f / sqrtf(var + 1e-3f);
  }
  __syncthreads();
  mean = red[8]; rstd = red[9];
}

// PhA: xa row via one-hot gather (t>0) or xa_t0 (t=0), + LN + ELU -> xe.
__device__ void phase_p1(const ScanArgs& a, int t, float* red, int* gidx) {
  const int row = blockIdx.x, tid = threadIdx.x;
  if (t > 0 && tid < 32) gidx[tid] = cloadi(a.idx + row * 32 + tid);
  __syncthreads();
  float mk = a.mask[t * 64 + row];
  float v[4];
  float s = 0.f, sq = 0.f;
#pragma unroll
  for (int i = 0; i < 4; i++) {
    int c = tid + (i << 8);
    float x = 0.f;
    if (c < 1000) {
      if (t == 0) {
        x = a.xa_t0[row * 1024 + c];
      } else {
        float g = 0.f;
#pragma unroll
        for (int s2 = 0; s2 < 32; s2++)
          g += a.zw[(s2 * 32 + gidx[s2]) * 1000 + c];
        x = g * mk + a.xa_base[(long)t * 65536 + row * 1024 + c];
      }
      s += x; sq += x * x;
    }
    v[i] = x;
  }
  float mean, rstd;
  ln_reduce(s, sq, red, mean, rstd);
#pragma unroll
  for (int i = 0; i < 4; i++) {
    int c = tid + (i << 8);
    float y = 0.f;
    if (c < 1000) {
      y = (v[i] - mean) * rstd * a.in_g[c] + a.in_b[c];
      y = y > 0.f ? y : expm1f(y);
    }
    cstore(a.xe + row * 1024 + c, y);
  }
  __syncthreads();
}

// PhE: sum 4 x2 partials + LN + ELU -> x2e.
__device__ void phase_x2e(const ScanArgs& a, float* red) {
  const int row = blockIdx.x, tid = threadIdx.x;
  float v[4];
  float s = 0.f, sq = 0.f;
#pragma unroll
  for (int i = 0; i < 4; i++) {
    int c = tid + (i << 8);
    float x = 0.f;
    if (c < 1000) {
#pragma unroll
      for (int q = 0; q < 4; q++)
        x += cload(a.x2_p + (long)q * 65536 + row * 1024 + c);
      s += x; sq += x * x;
    }
    v[i] = x;
  }
  float mean, rstd;
  ln_reduce(s, sq, red, mean, rstd);
#pragma unroll
  for (int i = 0; i < 4; i++) {
    int c = tid + (i << 8);
    float y = 0.f;
    if (c < 1000) {
      y = (v[i] - mean) * rstd * a.po_g[c] + a.po_b[c];
      y = y > 0.f ? y : expm1f(y);
    }
    cstore(a.x2e + row * 1024 + c, y);
  }
  __syncthreads();
}

// PhC: GRU gates (gi 2 partials, gh 4 partials), 2 adjacent d per thread.
__device__ void phase_gates(const ScanArgs& a, const float* hprev, int ldh,
                            const float* mk, float* feat_t, int t) {
  int p = blockIdx.x * 256 + threadIdx.x;  // 0..65535
  int b = p >> 10, d = (p & 1023) << 1;
  long gio = (long)b * 6144 + d;
  float r0 = 0.f, r1 = 0.f, z0 = 0.f, z1 = 0.f, n0 = 0.f, n1 = 0.f;
#pragma unroll
  for (int q = 0; q < 2; q++) {
    long o = (long)q * 393216 + gio;
    float2 t0 = cload2(a.gi_p + o);
    float2 t1 = cload2(a.gi_p + o + 2048);
    float2 t2 = cload2(a.gi_p + o + 4096);
    r0 += t0.x; r1 += t0.y; z0 += t1.x; z1 += t1.y; n0 += t2.x; n1 += t2.y;
  }
  r0 += a.gbi[d]; r1 += a.gbi[d + 1];
  z0 += a.gbi[d + 2048]; z1 += a.gbi[d + 2049];
  n0 += a.gbi[d + 4096]; n1 += a.gbi[d + 4097];
  float hr0 = a.gbh[d], hr1 = a.gbh[d + 1];
  float hz0 = a.gbh[d + 2048], hz1 = a.gbh[d + 2049];
  float hn0 = a.gbh[d + 4096], hn1 = a.gbh[d + 4097];
#pragma unroll
  for (int q = 0; q < 4; q++) {
    long o = (long)q * 393216 + gio;
    float2 t0 = cload2(a.gh_p + o);
    float2 t1 = cload2(a.gh_p + o + 2048);
    float2 t2 = cload2(a.gh_p + o + 4096);
    hr0 += t0.x; hr1 += t0.y; hz0 += t1.x; hz1 += t1.y; hn0 += t2.x; hn1 += t2.y;
  }
  float2 hp = cload2(hprev + (long)b * ldh + d);
  float m = mk[b];
  float rr0 = sigm(r0 + hr0), rr1 = sigm(r1 + hr1);
  float uu0 = sigm(z0 + hz0), uu1 = sigm(z1 + hz1);
  float nn0 = xla_tanh(n0 + rr0 * hn0), nn1 = xla_tanh(n1 + rr1 * hn1);
  float h0v = (1.f - uu0) * nn0 + uu0 * (hp.x * m);
  float h1v = (1.f - uu1) * nn1 + uu1 * (hp.y * m);
  cstore2(feat_t + (long)b * 3072 + d, h0v, h1v);
  if (t == 63) {
    a.hlast[(long)b * 2048 + d] = h0v;
    a.hlast[(long)b * 2048 + d + 1] = h1v;
  }
}

// PhF: pp GEMM (32x32 tile = one softmax group) fused with categorical
// sample. rg = row half (0/1), sg = stochastic group (0..31).
__device__ void phase_pp(const ScanArgs& a, int t, int rg, int sg,
                         float* As2, float* Bs2) {
  const int tid = threadIdx.x;
  const int ar = tid >> 3;            // A-stage row 0..31
  const int ak = (tid & 7) << 2;      // 4 k per thread
  const int bk = tid >> 3;            // B-stage k-row
  const int bc = (tid & 7) << 2;      // 4 cols
  const int rowBase = rg * 32, colBase = sg * 32;
  float acc[4] = {0.f, 0.f, 0.f, 0.f};
  float va[4], vb[4];

  auto ldA = [&](int kb) {
    const float* Ap = a.x2e + (long)(rowBase + ar) * 1024 + kb + ak;
    if (kb + ak + 3 < 1000) {
      float2 u0 = cload2(Ap), u1 = cload2(Ap + 2);
      va[0] = u0.x; va[1] = u0.y; va[2] = u1.x; va[3] = u1.y;
    } else {
#pragma unroll
      for (int i = 0; i < 4; i++)
        va[i] = (kb + ak + i < 1000) ? cload(Ap + i) : 0.f;
    }
  };
  auto ldB = [&](int kb) {
    int k = kb + bk;
    const float* Bp = a.pp_w + (long)k * 1024 + colBase + bc;
    if (k < 1000) {
      float4 u = *(const float4*)Bp;
      vb[0] = u.x; vb[1] = u.y; vb[2] = u.z; vb[3] = u.w;
    } else {
      vb[0] = vb[1] = vb[2] = vb[3] = 0.f;
    }
  };

  ldA(0); ldB(0);
  for (int kb = 0; kb < 1000; kb += 32) {
#pragma unroll
    for (int i = 0; i < 4; i++) As2[(ak + i) * 33 + ar] = va[i];
#pragma unroll
    for (int i = 0; i < 4; i++) Bs2[bk * 36 + bc + i] = vb[i];
    __syncthreads();
    if (kb + 32 < 1000) { ldA(kb + 32); ldB(kb + 32); }
#pragma unroll
    for (int kk = 0; kk < 32; kk++) {
      float av = As2[kk * 33 + ar];
      const float* bp = &Bs2[kk * 36 + bc];
#pragma unroll
      for (int j = 0; j < 4; j++) acc[j] += av * bp[j];
    }
    __syncthreads();
  }

  int b = rowBase + ar;
  float pp[4];
#pragma unroll
  for (int j = 0; j < 4; j++) pp[j] = acc[j] + a.pp_b[colBase + bc + j];
  *(float4*)&a.posts[(long)t * 65536 + (long)b * 1024 + colBase + bc] =
      make_float4(pp[0], pp[1], pp[2], pp[3]);

  uint2 kt = threefry(0u, 42u, 0u, (unsigned)t);
  const float TINY = 1.175494350822287508e-38f;
  float bs = -3.402823466e38f;
  int bj = 0;
#pragma unroll
  for (int j = 0; j < 4; j++) {
    unsigned gi_ = (unsigned)(b * 1024 + colBase + bc + j);
    uint2 o = threefry(kt.x, kt.y, 0u, gi_);
    unsigned bits = o.x ^ o.y;
    float u = __uint_as_float((bits >> 9) | 0x3f800000u) - 1.0f;
    u = fmaxf(TINY, u + TINY);
    float sc = pp[j] + -logf(-logf(u));
    if (sc > bs) { bs = sc; bj = bc + j; }
  }
#pragma unroll
  for (int off = 4; off >= 1; off >>= 1) {
    float os = __shfl_xor(bs, off, 8);
    int oj = __shfl_xor(bj, off, 8);
    if (os > bs || (os == bs && oj < bj)) { bs = os; bj = oj; }
  }
  float4 oh;
  float* op = (float*)&oh;
#pragma unroll
  for (int j = 0; j < 4; j++) op[j] = (bc + j == bj) ? 1.f : 0.f;
  *(float4*)&a.samples[(long)t * 65536 + (long)b * 1024 + colBase + bc] = oh;
  *(float4*)&a.feats[(long)t * 196608 + (long)b * 3072 + 2048 + colBase + bc] = oh;
  if (t == 63)
    *(float4*)&a.zlast[(long)b * 1024 + colBase + bc] = oh;
  if ((tid & 7) == 0) cstorei(a.idx + b * 32 + sg, bj);
}

__global__ __launch_bounds__(256, 2) void k_scan(ScanArgs a) {
  __shared__ float As[BK][LDP];
  __shared__ float Bs[BK][LDP];
  __shared__ float red[16];
  __shared__ int gidx[32];
  unsigned lgen = 0;
  const int bid = blockIdx.x;
  float* As2 = &As[0][0];
  float* Bs2 = &Bs[0][0];

  // Prologue: gh(0) quarters 0..3 from h0 (ldh 2048, mask row 0).
  if (bid < 384) {
    int tile = bid % 96, q = bid / 96;
    phase_gemm<TR_SCALEROW>(As, Bs, a.h0, 2048, a.gwh, 6144, q * 512,
                            q * 512 + 512, tile * 64, 6144, a.mask,
                            a.gh_p + (long)q * 393216, 6144, nullptr, nullptr);
  }
  gridbar(a.bar, lgen);

  for (int t = 0; t < 64; t++) {
    const float* hprev = t ? a.feats + (long)(t - 1) * 196608 : a.h0;
    int ldh = t ? 3072 : 2048;
    float* feat_t = a.feats + (long)t * 196608;

    // PhA: gather + LN + ELU -> xe (64 blocks)
    if (bid < 64) phase_p1(a, t, red, gidx);
    gridbar(a.bar, lgen);

    // PhB: gi split-2 (192) || gh(t) q3 from h(t-1) (96, t>=1)
    if (bid < 192) {
      int tile = bid % 96, ks = bid / 96;
      phase_gemm<TR_NONE>(As, Bs, a.xe, 1024, a.gwi, 6144, ks ? 512 : 0,
                          ks ? 1000 : 512, tile * 64, 6144, nullptr,
                          a.gi_p + (long)ks * 393216, 6144, nullptr, nullptr);
    } else if (bid < 288 && t >= 1) {
      int tile = bid - 192;
      phase_gemm<TR_SCALEROW>(As, Bs, hprev, 3072, a.gwh, 6144, 1536, 2048,
                              tile * 64, 6144, a.mask + t * 64,
                              a.gh_p + 3L * 393216, 6144, nullptr, nullptr);
    }
    gridbar(a.bar, lgen);

    // PhC: gates -> h(t) (256 blocks)
    if (bid < 256) phase_gates(a, hprev, ldh, a.mask + t * 64, feat_t, t);
    gridbar(a.bar, lgen);

    // PhD: x2 split-4 (64) || gh(t+1) q0 (96, t<63)
    if (bid < 64) {
      int ct = bid & 15, ks = bid >> 4;
      phase_gemm<TR_NONE>(As, Bs, feat_t, 3072, a.ph_w, 1000, ks * 512,
                          ks * 512 + 512, ct * 64, 1000, nullptr,
                          a.x2_p + (long)ks * 65536, 1024,
                          (ks == 0) ? a.x2_base + (long)t * 65536 : nullptr,
                          nullptr);
    } else if (bid < 160 && t < 63) {
      int tile = bid - 64;
      phase_gemm<TR_SCALEROW>(As, Bs, feat_t, 3072, a.gwh, 6144, 0, 512,
                              tile * 64, 6144, a.mask + (t + 1) * 64,
                              a.gh_p, 6144, nullptr, nullptr);
    }
    gridbar(a.bar, lgen);

    // PhE: x2e LN (64) || gh(t+1) q1 (96, t<63)
    if (bid < 64) phase_x2e(a, red);
    else if (bid < 160 && t < 63) {
      int tile = bid - 64;
      phase_gemm<TR_SCALEROW>(As, Bs, feat_t, 3072, a.gwh, 6144, 512, 1024,
                              tile * 64, 6144, a.mask + (t + 1) * 64,
                              a.gh_p + 1L * 393216, 6144, nullptr, nullptr);
    }
    gridbar(a.bar, lgen);

    // PhF: pp + sample (64) || gh(t+1) q2 (96, t<63)
    if (bid < 64) phase_pp(a, t, bid >> 5, bid & 31, As2, Bs2);
    else if (bid < 160 && t < 63) {
      int tile = bid - 64;
      phase_gemm<TR_SCALEROW>(As, Bs, feat_t, 3072, a.gwh, 6144, 1024, 1536,
                              tile * 64, 6144, a.mask + (t + 1) * 64,
                              a.gh_p + 2L * 393216, 6144, nullptr, nullptr);
    }
    gridbar(a.bar, lgen);
  }
}

// ======================= small helper kernels ==============================
__global__ void k_init(unsigned* bar) {
  int i = threadIdx.x;
  if (i < 512) bar[i] = 0u;
}

__global__ void k_detect(const unsigned* rr, int nDwordsSafe, int* fmt) {
  __shared__ int flags;
  if (threadIdx.x == 0) flags = 0;
  __syncthreads();
  int local = 0;
  for (int i = threadIdx.x; i < nDwordsSafe; i += 256) {
    unsigned dw = rr[i];
    if (dw == 0x3f800000u) local |= 4;
    else if (dw & 0xFFFFFF00u) local |= 1;
    else if (dw == 1u) local |= 2;
  }
  atomicOr(&flags, local);
  __syncthreads();
  if (threadIdx.x == 0) {
    int f = flags;
    *fmt = ((f & 4) == 0 && (f & 1)) ? 1 : 0;
  }
}

__global__ void k_prep(const void* rr, const int* fmt, float* mask, int n) {
  int i = blockIdx.x * 256 + threadIdx.x;
  if (i < n) {
    bool reset;
    if (*fmt == 1) reset = ((const unsigned char*)rr)[i] != 0;
    else reset = ((const int*)rr)[i] != 0;
    mask[i] = reset ? 0.0f : 1.0f;
  }
}

__global__ __launch_bounds__(256) void k_abase(const float* act, const float* aw,
                                               const float* zb, float* out) {
  for (long i = blockIdx.x * 256L + threadIdx.x; i < 4096L * 1024;
       i += (long)gridDim.x * 256) {
    int row = (int)(i >> 10), c = (int)(i & 1023);
    float v = 0.f;
    if (c < 1000) {
      v = zb[c];
#pragma unroll
      for (int k = 0; k < 6; k++) v += act[row * 6 + k] * aw[k * 1000 + c];
    }
    out[i] = v;
  }
}

// ---------------------------------------------------------------------------
extern "C" void kernel_launch(void* const* d_in, const int* in_sizes, int n_in,
                              void* d_out, int out_size, void* d_ws, size_t ws_size,
                              hipStream_t stream) {
  const float* embeds = (const float*)d_in[0];
  const float* actions = (const float*)d_in[1];
  const void* resets = d_in[2];
  const float* h0 = (const float*)d_in[3];
  const float* z0 = (const float*)d_in[4];
  const float* zw = (const float*)d_in[5];
  const float* zb = (const float*)d_in[6];
  const float* aw = (const float*)d_in[7];
  const float* in_g = (const float*)d_in[8];
  const float* in_b = (const float*)d_in[9];
  const float* gwi = (const float*)d_in[10];
  const float* gwh = (const float*)d_in[11];
  const float* gbi = (const float*)d_in[12];
  const float* gbh = (const float*)d_in[13];
  const float* ph_w = (const float*)d_in[14];
  const float* ph_b = (const float*)d_in[15];
  const float* pe_w = (const float*)d_in[16];
  const float* po_g = (const float*)d_in[17];
  const float* po_b = (const float*)d_in[18];
  const float* pp_w = (const float*)d_in[19];
  const float* pp_b = (const float*)d_in[20];
  const float* prh_w = (const float*)d_in[21];
  const float* prh_b = (const float*)d_in[22];
  const float* pr_g = (const float*)d_in[23];
  const float* pr_b = (const float*)d_in[24];
  const float* prp_w = (const float*)d_in[25];
  const float* prp_b = (const float*)d_in[26];

  float* out = (float*)d_out;
  float* priors  = out;
  float* posts   = out + 4194304;
  float* samples = out + 8388608;
  float* feats   = out + 12582912;
  float* hlast   = out + 25165824;
  float* zlast   = out + 25296896;

  float* ws = (float*)d_ws;
  unsigned* bar  = (unsigned*)ws;            // 512 u32
  int*   fmt     = (int*)(ws + 512);
  float* mask    = ws + 576;                 // 4096
  float* stats_p = ws + 4672;                // 8192
  float* xe      = ws + 12864;               // 65536
  float* x2e     = ws + 78400;               // 65536
  int*   idxb    = (int*)(ws + 143936);      // 2048
  float* xa_t0   = ws + 146048;              // 65536
  float* gi_p    = ws + 211584;              // 2*393216
  float* gh_p    = ws + 998016;              // 4*393216
  float* x2_p    = ws + 2570880;             // 4*65536
  float* xa_base = ws + 2833024;             // 4194304
  float* x2_base = ws + 7027328;             // 4194304
  float* xp      = ws + 11221632;            // 4194304 (end ~61.7 MB)

  k_init<<<1, 512, 0, stream>>>(bar);
  k_detect<<<1, 256, 0, stream>>>((const unsigned*)resets, 1024, fmt);
  k_prep<<<16, 256, 0, stream>>>(resets, fmt, mask, 4096);
  k_abase<<<2048, 256, 0, stream>>>(actions, aw, zb, xa_base);

  // xa_t0 = (z0*m0)@zw + zb + a0@aw (dense z0 path)
  GemmArgs g0{};
  g0.A = z0; g0.lda = 1024; g0.B = zw; g0.ldb = 1000; g0.K = 1024; g0.ksplit = 1;
  g0.A2 = actions; g0.lda2 = 6; g0.B2 = aw; g0.ldb2 = 1000; g0.K2 = 6;
  g0.N = 1000; g0.bias = zb; g0.t1s = mask;
  g0.C = xa_t0; g0.ldc = 1024; g0.partStride = 0;
  k_gemm<TR_SCALEROW, TR_NONE><<<dim3(16, 1, 1), 256, 0, stream>>>(g0);

  // x2_base = embeds @ pe_w + ph_b
  GemmArgs ge{};
  ge.A = embeds; ge.lda = 1024; ge.B = pe_w; ge.ldb = 1000; ge.K = 1024; ge.ksplit = 1;
  ge.N = 1000; ge.bias = ph_b; ge.C = x2_base; ge.ldc = 1024; ge.partStride = 0;
  k_gemm<TR_NONE, TR_NONE><<<dim3(16, 1, 64), 256, 0, stream>>>(ge);

  // persistent 64-step scan
  ScanArgs sa{};
  sa.h0 = h0; sa.zw = zw; sa.gwi = gwi; sa.gwh = gwh;
  sa.gbi = gbi; sa.gbh = gbh; sa.ph_w = ph_w; sa.pp_w = pp_w; sa.pp_b = pp_b;
  sa.in_g = in_g; sa.in_b = in_b; sa.po_g = po_g; sa.po_b = po_b;
  sa.mask = mask; sa.xa_base = xa_base; sa.x2_base = x2_base; sa.xa_t0 = xa_t0;
  sa.gi_p = gi_p; sa.gh_p = gh_p; sa.x2_p = x2_p;
  sa.xe = xe; sa.x2e = x2e; sa.idx = idxb;
  sa.posts = posts; sa.samples = samples; sa.feats = feats;
  sa.hlast = hlast; sa.zlast = zlast; sa.bar = bar;
  k_scan<<<NBLK, 256, 0, stream>>>(sa);

  // prior head (batched over all T*B rows)
  GemmArgs gp1{};
  gp1.A = feats; gp1.lda = 3072; gp1.B = prh_w; gp1.ldb = 1000; gp1.K = 2048; gp1.ksplit = 1;
  gp1.N = 1000; gp1.bias = prh_b; gp1.C = xp; gp1.ldc = 1024; gp1.partStride = 0;
  k_gemm<TR_NONE, TR_NONE><<<dim3(16, 1, 64), 256, 0, stream>>>(gp1);
  k_prstat<<<1024, 256, 0, stream>>>(xp, stats_p, 1000);
  GemmArgs gp2{};
  gp2.A = xp; gp2.lda = 1024; gp2.B = prp_w; gp2.ldb = 1024; gp2.K = 1000; gp2.ksplit = 1;
  gp2.N = 1024; gp2.bias = prp_b; gp2.t1s = stats_p; gp2.t1g = pr_g; gp2.t1b = pr_b;
  gp2.C = priors; gp2.ldc = 1024; gp2.partStride = 0;
  k_gemm<TR_LNELU, TR_NONE><<<dim3(16, 1, 64), 256, 0, stream>>>(gp2);
}

// Round 5
// 21409.981 us; speedup vs baseline: 1.2529x; 1.2529x over previous
//
#include <hip/hip_runtime.h>
#include <hip/hip_bf16.h>

// ---------------------------------------------------------------------------
// RSSMCore multi-kernel v2 (R5).
// R2-R4 lesson: persistent + grid barriers on gfx950 loses either to
// agent-acquire L2-invalidate storms (R2) or to sc0sc1 coherent-path latency
// with A-operand broadcast amplification (R3/R4). Multi-kernel dispatch gets
// cross-XCD coherence free at kernel boundaries -> all loads normally cached.
// 5 launches/step: gather | gi | gates | x2+gh(t+1) | LN+pp+sample(fused).
// All fp32 (no fp32 MFMA on CDNA4; bf16 would flip categorical argmax).
// ---------------------------------------------------------------------------

#define BK 32
#define LDP 66

enum { TR_NONE = 0, TR_SCALEROW = 1, TR_LNELU = 2 };

// XLA f32 tanh rational approximation (mul/add, no contraction) -------------
__device__ inline float xla_tanh(float x) {
  float ax = fabsf(x);
  float xc = fminf(fmaxf(x, -7.90531110763549805f), 7.90531110763549805f);
  float x2 = __fmul_rn(xc, xc);
  float p = -2.76076847742355e-16f;
  p = __fadd_rn(__fmul_rn(p, x2), 2.00018790482477e-13f);
  p = __fadd_rn(__fmul_rn(p, x2), -8.60467152213735e-11f);
  p = __fadd_rn(__fmul_rn(p, x2), 5.12229709037114e-08f);
  p = __fadd_rn(__fmul_rn(p, x2), 1.48572235717979e-05f);
  p = __fadd_rn(__fmul_rn(p, x2), 6.37261928875436e-04f);
  p = __fadd_rn(__fmul_rn(p, x2), 4.89352455891786e-03f);
  float num = __fmul_rn(xc, p);
  float q = 1.19825839466702e-06f;
  q = __fadd_rn(__fmul_rn(q, x2), 1.18534705686654e-04f);
  q = __fadd_rn(__fmul_rn(q, x2), 2.26843463243900e-03f);
  q = __fadd_rn(__fmul_rn(q, x2), 4.89352518554385e-03f);
  float r = __fdiv_rn(num, q);
  return ax < 0.0004f ? x : r;
}

__device__ inline float sigm(float x) { return 1.0f / (1.0f + expf(-x)); }

// Threefry2x32 (20 rounds), matches jax/_src/prng.py ------------------------
__device__ inline void tfround(unsigned& x0, unsigned& x1, int r) {
  x0 += x1; x1 = (x1 << r) | (x1 >> (32 - r)); x1 ^= x0;
}
__device__ inline uint2 threefry(unsigned k0, unsigned k1, unsigned c0, unsigned c1) {
  unsigned ks2 = k0 ^ k1 ^ 0x1BD11BDAu;
  unsigned x0 = c0 + k0, x1 = c1 + k1;
  tfround(x0, x1, 13); tfround(x0, x1, 15); tfround(x0, x1, 26); tfround(x0, x1, 6);
  x0 += k1; x1 += ks2 + 1u;
  tfround(x0, x1, 17); tfround(x0, x1, 29); tfround(x0, x1, 16); tfround(x0, x1, 24);
  x0 += ks2; x1 += k0 + 2u;
  tfround(x0, x1, 13); tfround(x0, x1, 15); tfround(x0, x1, 26); tfround(x0, x1, 6);
  x0 += k0; x1 += k1 + 3u;
  tfround(x0, x1, 17); tfround(x0, x1, 29); tfround(x0, x1, 16); tfround(x0, x1, 24);
  x0 += k1; x1 += ks2 + 4u;
  tfround(x0, x1, 13); tfround(x0, x1, 15); tfround(x0, x1, 26); tfround(x0, x1, 6);
  x0 += ks2; x1 += k0 + 5u;
  return make_uint2(x0, x1);
}

// ======================= generic tiled GEMM (pre/post path) ================
struct GemmArgs {
  const float* A; int lda; const float* B; int ldb; int K; int ksplit;
  const float* A2; int lda2; const float* B2; int ldb2; int K2;
  int N; const float* bias;
  const float* t1s; const float* t1g; const float* t1b;
  float* C; int ldc; long partStride;
};

template <int TRA>
__device__ void gemm_tiles(float acc[4][4], float (*As)[LDP], float (*Bs)[LDP],
                           const float* A, int lda, const float* B, int ldb,
                           int kB, int kE, int mBase, int cBase, int N,
                           const float* s0, const float* g0, const float* b0) {
  const int tid = threadIdx.x;
  const int ar = tid >> 2;
  const int ak = (tid & 3) << 3;
  const int bk = tid >> 3;
  const int bc = (tid & 7) << 3;
  const int r0 = (tid >> 4) << 2;
  const int c0 = (tid & 15) << 2;

  float rowS = 1.f, rowM = 0.f, rowR = 1.f;
  if (TRA == TR_SCALEROW) rowS = s0[mBase + ar];
  else if (TRA == TR_LNELU) {
    rowM = s0[(mBase + ar) * 2];
    rowR = s0[(mBase + ar) * 2 + 1];
  }

  for (int kb = kB; kb < kE; kb += BK) {
    {
      const float* Ap = A + (long)(mBase + ar) * lda + kb + ak;
      float v[8];
      if (kb + ak + 7 < kE) {
        float4 u0 = *(const float4*)(Ap);
        float4 u1 = *(const float4*)(Ap + 4);
        v[0] = u0.x; v[1] = u0.y; v[2] = u0.z; v[3] = u0.w;
        v[4] = u1.x; v[5] = u1.y; v[6] = u1.z; v[7] = u1.w;
      } else {
#pragma unroll
        for (int i = 0; i < 8; i++) v[i] = (kb + ak + i < kE) ? Ap[i] : 0.f;
      }
#pragma unroll
      for (int i = 0; i < 8; i++) {
        int k = kb + ak + i;
        float x = 0.f;
        if (k < kE) {
          x = v[i];
          if (TRA == TR_SCALEROW) {
            x *= rowS;
          } else if (TRA == TR_LNELU) {
            x = (x - rowM) * rowR * g0[k] + b0[k];
            x = x > 0.f ? x : expm1f(x);
          }
        }
        As[ak + i][ar] = x;
      }
    }
    {
      int k = kb + bk;
      const float* Bp = B + (long)k * ldb + cBase + bc;
      if (k < kE && cBase + bc + 7 < N) {
        float4 u0 = *(const float4*)(Bp);
        float4 u1 = *(const float4*)(Bp + 4);
        Bs[bk][bc + 0] = u0.x; Bs[bk][bc + 1] = u0.y;
        Bs[bk][bc + 2] = u0.z; Bs[bk][bc + 3] = u0.w;
        Bs[bk][bc + 4] = u1.x; Bs[bk][bc + 5] = u1.y;
        Bs[bk][bc + 6] = u1.z; Bs[bk][bc + 7] = u1.w;
      } else {
#pragma unroll
        for (int i = 0; i < 8; i++)
          Bs[bk][bc + i] = (k < kE && cBase + bc + i < N) ? Bp[i] : 0.f;
      }
    }
    __syncthreads();
#pragma unroll
    for (int kk = 0; kk < BK; kk++) {
      float4 a4 = *(const float4*)&As[kk][r0];
      float4 b4 = *(const float4*)&Bs[kk][c0];
      float av[4] = {a4.x, a4.y, a4.z, a4.w};
      float bv[4] = {b4.x, b4.y, b4.z, b4.w};
#pragma unroll
      for (int i = 0; i < 4; i++)
#pragma unroll
        for (int j = 0; j < 4; j++) acc[i][j] += av[i] * bv[j];
    }
    __syncthreads();
  }
}

template <int TRA, int TRA2>
__global__ __launch_bounds__(256) void k_gemm(GemmArgs g) {
  __shared__ float As[BK][LDP];
  __shared__ float Bs[BK][LDP];
  const int nT = blockIdx.x, ks = blockIdx.y, mT = blockIdx.z;
  const int mBase = mT * 64, cBase = nT * 64;
  float acc[4][4] = {};
  int chunk = (((g.K + g.ksplit - 1) / g.ksplit) + 31) & ~31;
  int kB = ks * chunk, kE = min(g.K, kB + chunk);
  if (kB < kE)
    gemm_tiles<TRA>(acc, As, Bs, g.A, g.lda, g.B, g.ldb, kB, kE, mBase, cBase,
                    g.N, g.t1s, g.t1g, g.t1b);
  if (g.A2) {
    int chunk2 = (((g.K2 + g.ksplit - 1) / g.ksplit) + 31) & ~31;
    int kB2 = ks * chunk2, kE2 = min(g.K2, kB2 + chunk2);
    if (kB2 < kE2)
      gemm_tiles<TRA2>(acc, As, Bs, g.A2, g.lda2, g.B2, g.ldb2, kB2, kE2, mBase,
                       cBase, g.N, nullptr, nullptr, nullptr);
  }
  const int tid = threadIdx.x;
  const int r0 = (tid >> 4) << 2, c0 = (tid & 15) << 2;
  float* Cb = g.C + (long)ks * g.partStride;
#pragma unroll
  for (int i = 0; i < 4; i++) {
    float4 v = make_float4(acc[i][0], acc[i][1], acc[i][2], acc[i][3]);
    if (ks == 0 && g.bias) {
      int c = cBase + c0;
      v.x += (c + 0 < g.N) ? g.bias[c + 0] : 0.f;
      v.y += (c + 1 < g.N) ? g.bias[c + 1] : 0.f;
      v.z += (c + 2 < g.N) ? g.bias[c + 2] : 0.f;
      v.w += (c + 3 < g.N) ? g.bias[c + 3] : 0.f;
    }
    *(float4*)&Cb[(long)(mBase + r0 + i) * g.ldc + cBase + c0] = v;
  }
}

__global__ __launch_bounds__(256) void k_prstat(const float* xp, float* stats, int N) {
  int wave = threadIdx.x >> 6, lane = threadIdx.x & 63;
  int r = blockIdx.x * 4 + wave;
  float s = 0.f, sq = 0.f;
  for (int c = lane; c < N; c += 64) {
    float v = xp[(long)r * 1024 + c];
    s += v; sq += v * v;
  }
#pragma unroll
  for (int off = 32; off >= 1; off >>= 1) {
    s += __shfl_down(s, off);
    sq += __shfl_down(sq, off);
  }
  if (lane == 0) {
    float mean = s / N, var = sq / N - mean * mean;
    stats[r * 2] = mean;
    stats[r * 2 + 1] = 1.0f / sqrtf(var + 1e-3f);
  }
}

// ============== 64x64 single-chunk tile GEMM, plain cached loads ===========
template <int TRA>
__device__ void tile_gemm(float (*As)[LDP], float (*Bs)[LDP],
                          const float* A, int lda, const float* B, int ldb,
                          int kB, int kE, int cBase, int N,
                          const float* rowScale, float* C, int ldc,
                          const float* baseAdd, const float* colBias) {
  const int tid = threadIdx.x;
  const int ar = tid >> 2, ak = (tid & 3) << 3;
  const int bk = tid >> 3, bc = (tid & 7) << 3;
  const int r0 = (tid >> 4) << 2, c0 = (tid & 15) << 2;
  float acc[4][4] = {};
  float rowS = (TRA == TR_SCALEROW) ? rowScale[ar] : 1.f;
  float v[8], w[8];

  auto ldA = [&](int kb) {
    const float* Ap = A + (long)ar * lda + kb + ak;
    if (kb + ak + 7 < kE) {
      float4 u0 = *(const float4*)(Ap);
      float4 u1 = *(const float4*)(Ap + 4);
      v[0] = u0.x; v[1] = u0.y; v[2] = u0.z; v[3] = u0.w;
      v[4] = u1.x; v[5] = u1.y; v[6] = u1.z; v[7] = u1.w;
    } else {
#pragma unroll
      for (int i = 0; i < 8; i++) v[i] = (kb + ak + i < kE) ? Ap[i] : 0.f;
    }
  };
  auto ldB = [&](int kb) {
    int k = kb + bk;
    const float* Bp = B + (long)k * ldb + cBase + bc;
    if (k < kE && cBase + bc + 7 < N) {
      float4 u0 = *(const float4*)(Bp);
      float4 u1 = *(const float4*)(Bp + 4);
      w[0] = u0.x; w[1] = u0.y; w[2] = u0.z; w[3] = u0.w;
      w[4] = u1.x; w[5] = u1.y; w[6] = u1.z; w[7] = u1.w;
    } else {
#pragma unroll
      for (int i = 0; i < 8; i++)
        w[i] = (k < kE && cBase + bc + i < N) ? Bp[i] : 0.f;
    }
  };

  ldA(kB); ldB(kB);
  for (int kb = kB; kb < kE; kb += BK) {
#pragma unroll
    for (int i = 0; i < 8; i++)
      As[ak + i][ar] = (TRA == TR_SCALEROW) ? v[i] * rowS : v[i];
#pragma unroll
    for (int i = 0; i < 8; i++) Bs[bk][bc + i] = w[i];
    __syncthreads();
    if (kb + BK < kE) { ldA(kb + BK); ldB(kb + BK); }
#pragma unroll
    for (int kk = 0; kk < BK; kk++) {
      float4 a4 = *(const float4*)&As[kk][r0];
      float4 b4 = *(const float4*)&Bs[kk][c0];
      float av[4] = {a4.x, a4.y, a4.z, a4.w};
      float bv[4] = {b4.x, b4.y, b4.z, b4.w};
#pragma unroll
      for (int i = 0; i < 4; i++)
#pragma unroll
        for (int j = 0; j < 4; j++) acc[i][j] += av[i] * bv[j];
    }
    __syncthreads();
  }

#pragma unroll
  for (int i = 0; i < 4; i++) {
    float4 v4 = make_float4(acc[i][0], acc[i][1], acc[i][2], acc[i][3]);
    int c = cBase + c0;
    if (baseAdd) {
      const float* bp = baseAdd + (long)(r0 + i) * 1024 + c;
      v4.x += (c + 0 < N) ? bp[0] : 0.f;
      v4.y += (c + 1 < N) ? bp[1] : 0.f;
      v4.z += (c + 2 < N) ? bp[2] : 0.f;
      v4.w += (c + 3 < N) ? bp[3] : 0.f;
    }
    if (colBias) {
      v4.x += (c + 0 < N) ? colBias[c + 0] : 0.f;
      v4.y += (c + 1 < N) ? colBias[c + 1] : 0.f;
      v4.z += (c + 2 < N) ? colBias[c + 2] : 0.f;
      v4.w += (c + 3 < N) ? colBias[c + 3] : 0.f;
    }
    *(float4*)&C[(long)(r0 + i) * ldc + cBase + c0] = v4;
  }
}

// Block-wide LN helper (N=1000, thread covers cols tid, tid+256, ...)
__device__ inline void ln_reduce(float s, float sq, float* red, float& mean,
                                 float& rstd) {
  const int tid = threadIdx.x;
#pragma unroll
  for (int off = 32; off >= 1; off >>= 1) {
    s += __shfl_down(s, off);
    sq += __shfl_down(sq, off);
  }
  if ((tid & 63) == 0) { red[tid >> 6] = s; red[4 + (tid >> 6)] = sq; }
  __syncthreads();
  if (tid == 0) {
    float S = red[0] + red[1] + red[2] + red[3];
    float Q = red[4] + red[5] + red[6] + red[7];
    float m = S / 1000.f;
    float var = Q / 1000.f - m * m;
    red[8] = m;
    red[9] = 1.f / sqrtf(var + 1e-3f);
  }
  __syncthreads();
  mean = red[8]; rstd = red[9];
}

// ===== A: gather (z one-hot @ zw) + inline a@aw+zb + LN + ELU -> xe ========
__global__ __launch_bounds__(256) void k_gather(
    const float* zw, const float* aw, const float* zb, const float* act_t,
    const float* xa_t0, const float* in_g, const float* in_b,
    const float* mask_t, const int* idx, float* xe, int t) {
  __shared__ float red[16];
  __shared__ int gidx[32];
  __shared__ float arow[6];
  const int row = blockIdx.x, tid = threadIdx.x;
  if (t > 0) {
    if (tid < 32) gidx[tid] = idx[row * 32 + tid];
    if (tid >= 32 && tid < 38) arow[tid - 32] = act_t[row * 6 + (tid - 32)];
  }
  __syncthreads();
  float mk = mask_t[row];
  float v[4];
  float s = 0.f, sq = 0.f;
#pragma unroll
  for (int i = 0; i < 4; i++) {
    int c = tid + (i << 8);
    float x = 0.f;
    if (c < 1000) {
      if (t == 0) {
        x = xa_t0[row * 1024 + c];
      } else {
        float g = 0.f;
#pragma unroll
        for (int s2 = 0; s2 < 32; s2++)
          g += zw[(s2 * 32 + gidx[s2]) * 1000 + c];
        float ab = zb[c];
#pragma unroll
        for (int k = 0; k < 6; k++) ab += arow[k] * aw[k * 1000 + c];
        x = g * mk + ab;
      }
      s += x; sq += x * x;
    }
    v[i] = x;
  }
  float mean, rstd;
  ln_reduce(s, sq, red, mean, rstd);
#pragma unroll
  for (int i = 0; i < 4; i++) {
    int c = tid + (i << 8);
    float y = 0.f;
    if (c < 1000) {
      y = (v[i] - mean) * rstd * in_g[c] + in_b[c];
      y = y > 0.f ? y : expm1f(y);
    }
    xe[row * 1024 + c] = y;
  }
}

// ===== B: gi = xe @ gru_wi, split-5 (chunks of 200), 480 blocks ============
__global__ __launch_bounds__(256) void k_gigemm(const float* xe, const float* gwi,
                                                float* gi_p) {
  __shared__ float As[BK][LDP];
  __shared__ float Bs[BK][LDP];
  int tile = blockIdx.x % 96, ks = blockIdx.x / 96;
  int kB = ks * 200, kE = kB + 200;
  tile_gemm<TR_NONE>(As, Bs, xe, 1024, gwi, 6144, kB, kE, tile * 64, 6144,
                     nullptr, gi_p + (long)ks * 393216, 6144, nullptr, nullptr);
}

// ===== C: gates (5 gi + 4 gh partials) -> h(t), 512 blocks =================
__global__ __launch_bounds__(256) void k_gates(
    const float* gi_p, const float* gh_p, const float* gbi, const float* gbh,
    const float* hprev, int ldh, const float* mask_t, float* feats_t,
    float* hlast, int t) {
  int i = blockIdx.x * 256 + threadIdx.x;  // 0..131071
  int b = i >> 11, d = i & 2047;
  long gio = (long)b * 6144 + d;
  float gr = gbi[d], gz = gbi[d + 2048], gn = gbi[d + 4096];
#pragma unroll
  for (int p = 0; p < 5; p++) {
    long o = (long)p * 393216 + gio;
    gr += gi_p[o]; gz += gi_p[o + 2048]; gn += gi_p[o + 4096];
  }
  float hr = gbh[d], hz = gbh[d + 2048], hn = gbh[d + 4096];
#pragma unroll
  for (int p = 0; p < 4; p++) {
    long o = (long)p * 393216 + gio;
    hr += gh_p[o]; hz += gh_p[o + 2048]; hn += gh_p[o + 4096];
  }
  float hm = hprev[(long)b * ldh + d] * mask_t[b];
  float r = sigm(gr + hr);
  float u = sigm(gz + hz);
  float n = xla_tanh(gn + r * hn);
  float h = (1.f - u) * n + u * hm;
  feats_t[(long)b * 3072 + d] = h;
  if (t == 63) hlast[(long)b * 2048 + d] = h;
}

// ===== D: x2 split-8 (128 blk) + gh(next) split-4 (384 blk) ================
__global__ __launch_bounds__(256) void k_x2gh(
    const float* hA, int ldh, const float* gwh, const float* mask_next,
    const float* ph_w, const float* x2_base_t, float* gh_p, float* x2_p,
    int ghOn, int x2On) {
  __shared__ float As[BK][LDP];
  __shared__ float Bs[BK][LDP];
  const int bid = blockIdx.x;
  if (bid < 384) {
    if (!ghOn) return;
    int tile = bid % 96, ks = bid / 96;
    int kB = ks * 512, kE = kB + 512;
    tile_gemm<TR_SCALEROW>(As, Bs, hA, ldh, gwh, 6144, kB, kE, tile * 64, 6144,
                           mask_next, gh_p + (long)ks * 393216, 6144, nullptr,
                           nullptr);
  } else {
    if (!x2On) return;
    int i2 = bid - 384;
    int ct = i2 & 15, ks = i2 >> 4;
    int kB = ks * 256, kE = kB + 256;
    tile_gemm<TR_NONE>(As, Bs, hA, ldh, ph_w, 1000, kB, kE, ct * 64, 1000,
                       nullptr, x2_p + (long)ks * 65536, 1024,
                       (ks == 0) ? x2_base_t : nullptr, nullptr);
  }
}

// ===== E: fused x2-merge + LN + ELU + pp GEMM(32x32) + threefry sample =====
__global__ __launch_bounds__(256) void k_ppfuse(
    const float* x2_p, const float* pp_w, const float* pp_b, const float* po_g,
    const float* po_b, float* posts_t, float* samples_t, float* feats_t,
    float* zlast, int* idx, int t) {
  __shared__ float stats[32][2];
  __shared__ float As2[32 * 33];
  __shared__ float Bs2[32 * 36];
  const int tid = threadIdx.x;
  const int rg = blockIdx.x >> 5, sg = blockIdx.x & 31;
  const int rowBase = rg * 32, colBase = sg * 32;

  // pass 1: row LN stats over merged x2 (8 threads per row)
  {
    int r8 = tid >> 3, c8 = tid & 7;
    const float* base = x2_p + (long)(rowBase + r8) * 1024;
    float s = 0.f, sq = 0.f;
    for (int c = c8 * 4; c < 1000; c += 32) {
      float4 a4 = make_float4(0.f, 0.f, 0.f, 0.f);
#pragma unroll
      for (int p = 0; p < 8; p++) {
        float4 u = *(const float4*)(base + (long)p * 65536 + c);
        a4.x += u.x; a4.y += u.y; a4.z += u.z; a4.w += u.w;
      }
      s += a4.x + a4.y + a4.z + a4.w;
      sq += a4.x * a4.x + a4.y * a4.y + a4.z * a4.z + a4.w * a4.w;
    }
#pragma unroll
    for (int off = 4; off >= 1; off >>= 1) {
      s += __shfl_xor(s, off, 8);
      sq += __shfl_xor(sq, off, 8);
    }
    if (c8 == 0) {
      float mean = s / 1000.f;
      float var = sq / 1000.f - mean * mean;
      stats[r8][0] = mean;
      stats[r8][1] = 1.f / sqrtf(var + 1e-3f);
    }
  }
  __syncthreads();

  // pass 2: GEMM  elu(ln(x2)) @ pp_w  for this 32x32 tile
  const int ar = tid >> 3, ak = (tid & 7) << 2;
  const int bk = tid >> 3, bc = (tid & 7) << 2;
  float acc[4] = {0.f, 0.f, 0.f, 0.f};
  float mean = stats[ar][0], rstd = stats[ar][1];
  const float* abase = x2_p + (long)(rowBase + ar) * 1024;
  for (int kb = 0; kb < 1000; kb += 32) {
    {
      float va[4] = {0.f, 0.f, 0.f, 0.f};
      if (kb + ak + 3 < 1000) {
#pragma unroll
        for (int p = 0; p < 8; p++) {
          float4 u = *(const float4*)(abase + (long)p * 65536 + kb + ak);
          va[0] += u.x; va[1] += u.y; va[2] += u.z; va[3] += u.w;
        }
      }
#pragma unroll
      for (int i = 0; i < 4; i++) {
        int k = kb + ak + i;
        float y = 0.f;
        if (k < 1000) {
          y = (va[i] - mean) * rstd * po_g[k] + po_b[k];
          y = y > 0.f ? y : expm1f(y);
        }
        As2[(ak + i) * 33 + ar] = y;
      }
    }
    {
      int k = kb + bk;
      if (k < 1000) {
        float4 u = *(const float4*)(pp_w + (long)k * 1024 + colBase + bc);
        Bs2[bk * 36 + bc + 0] = u.x; Bs2[bk * 36 + bc + 1] = u.y;
        Bs2[bk * 36 + bc + 2] = u.z; Bs2[bk * 36 + bc + 3] = u.w;
      } else {
        Bs2[bk * 36 + bc + 0] = 0.f; Bs2[bk * 36 + bc + 1] = 0.f;
        Bs2[bk * 36 + bc + 2] = 0.f; Bs2[bk * 36 + bc + 3] = 0.f;
      }
    }
    __syncthreads();
#pragma unroll
    for (int kk = 0; kk < 32; kk++) {
      float av = As2[kk * 33 + ar];
      const float* bp = &Bs2[kk * 36 + bc];
#pragma unroll
      for (int j = 0; j < 4; j++) acc[j] += av * bp[j];
    }
    __syncthreads();
  }

  // epilogue: posts + JAX-exact categorical straight-through sample
  int b = rowBase + ar;
  float pp[4];
#pragma unroll
  for (int j = 0; j < 4; j++) pp[j] = acc[j] + pp_b[colBase + bc + j];
  *(float4*)&posts_t[(long)b * 1024 + colBase + bc] =
      make_float4(pp[0], pp[1], pp[2], pp[3]);

  uint2 kt = threefry(0u, 42u, 0u, (unsigned)t);
  const float TINY = 1.175494350822287508e-38f;
  float bs = -3.402823466e38f;
  int bj = 0;
#pragma unroll
  for (int j = 0; j < 4; j++) {
    unsigned gi_ = (unsigned)(b * 1024 + colBase + bc + j);
    uint2 o = threefry(kt.x, kt.y, 0u, gi_);
    unsigned bits = o.x ^ o.y;
    float u = __uint_as_float((bits >> 9) | 0x3f800000u) - 1.0f;
    u = fmaxf(TINY, u + TINY);
    float sc = pp[j] + -logf(-logf(u));
    if (sc > bs) { bs = sc; bj = bc + j; }
  }
#pragma unroll
  for (int off = 4; off >= 1; off >>= 1) {
    float os = __shfl_xor(bs, off, 8);
    int oj = __shfl_xor(bj, off, 8);
    if (os > bs || (os == bs && oj < bj)) { bs = os; bj = oj; }
  }
  float4 oh;
  float* op = (float*)&oh;
#pragma unroll
  for (int j = 0; j < 4; j++) op[j] = (bc + j == bj) ? 1.f : 0.f;
  *(float4*)&samples_t[(long)b * 1024 + colBase + bc] = oh;
  *(float4*)&feats_t[(long)b * 3072 + 2048 + colBase + bc] = oh;
  if (t == 63) *(float4*)&zlast[(long)b * 1024 + colBase + bc] = oh;
  if ((tid & 7) == 0) idx[b * 32 + sg] = bj;
}

// ======================= small helper kernels ==============================
__global__ void k_detect(const unsigned* rr, int nDwordsSafe, int* fmt) {
  __shared__ int flags;
  if (threadIdx.x == 0) flags = 0;
  __syncthreads();
  int local = 0;
  for (int i = threadIdx.x; i < nDwordsSafe; i += 256) {
    unsigned dw = rr[i];
    if (dw == 0x3f800000u) local |= 4;
    else if (dw & 0xFFFFFF00u) local |= 1;
    else if (dw == 1u) local |= 2;
  }
  atomicOr(&flags, local);
  __syncthreads();
  if (threadIdx.x == 0) {
    int f = flags;
    *fmt = ((f & 4) == 0 && (f & 1)) ? 1 : 0;
  }
}

__global__ void k_prep(const void* rr, const int* fmt, float* mask, int n) {
  int i = blockIdx.x * 256 + threadIdx.x;
  if (i < n) {
    bool reset;
    if (*fmt == 1) reset = ((const unsigned char*)rr)[i] != 0;
    else reset = ((const int*)rr)[i] != 0;
    mask[i] = reset ? 0.0f : 1.0f;
  }
}

// ---------------------------------------------------------------------------
extern "C" void kernel_launch(void* const* d_in, const int* in_sizes, int n_in,
                              void* d_out, int out_size, void* d_ws, size_t ws_size,
                              hipStream_t stream) {
  const float* embeds = (const float*)d_in[0];
  const float* actions = (const float*)d_in[1];
  const void* resets = d_in[2];
  const float* h0 = (const float*)d_in[3];
  const float* z0 = (const float*)d_in[4];
  const float* zw = (const float*)d_in[5];
  const float* zb = (const float*)d_in[6];
  const float* aw = (const float*)d_in[7];
  const float* in_g = (const float*)d_in[8];
  const float* in_b = (const float*)d_in[9];
  const float* gwi = (const float*)d_in[10];
  const float* gwh = (const float*)d_in[11];
  const float* gbi = (const float*)d_in[12];
  const float* gbh = (const float*)d_in[13];
  const float* ph_w = (const float*)d_in[14];
  const float* ph_b = (const float*)d_in[15];
  const float* pe_w = (const float*)d_in[16];
  const float* po_g = (const float*)d_in[17];
  const float* po_b = (const float*)d_in[18];
  const float* pp_w = (const float*)d_in[19];
  const float* pp_b = (const float*)d_in[20];
  const float* prh_w = (const float*)d_in[21];
  const float* prh_b = (const float*)d_in[22];
  const float* pr_g = (const float*)d_in[23];
  const float* pr_b = (const float*)d_in[24];
  const float* prp_w = (const float*)d_in[25];
  const float* prp_b = (const float*)d_in[26];

  float* out = (float*)d_out;
  float* priors  = out;
  float* posts   = out + 4194304;
  float* samples = out + 8388608;
  float* feats   = out + 12582912;
  float* hlast   = out + 25165824;
  float* zlast   = out + 25296896;

  float* ws = (float*)d_ws;
  int*   fmt     = (int*)ws;
  float* mask    = ws + 64;                  // 4096
  float* stats_p = ws + 4160;                // 8192
  float* xe      = ws + 12352;               // 65536
  int*   idxb    = (int*)(ws + 77888);       // 2048
  float* xa_t0   = ws + 79936;               // 65536
  float* gi_p    = ws + 145472;              // 5*393216 = 1966080
  float* gh_p    = ws + 2111552;             // 4*393216 = 1572864
  float* x2_p    = ws + 3684416;             // 8*65536  = 524288
  float* x2_base = ws + 4208704;             // 4194304
  float* xp      = ws + 8403008;             // 4194304 (end ~50.4 MB)

  k_detect<<<1, 256, 0, stream>>>((const unsigned*)resets, 1024, fmt);
  k_prep<<<16, 256, 0, stream>>>(resets, fmt, mask, 4096);

  // xa_t0 = (z0*m0)@zw + zb + a0@aw (dense z0 path, once)
  GemmArgs g0{};
  g0.A = z0; g0.lda = 1024; g0.B = zw; g0.ldb = 1000; g0.K = 1024; g0.ksplit = 1;
  g0.A2 = actions; g0.lda2 = 6; g0.B2 = aw; g0.ldb2 = 1000; g0.K2 = 6;
  g0.N = 1000; g0.bias = zb; g0.t1s = mask;
  g0.C = xa_t0; g0.ldc = 1024; g0.partStride = 0;
  k_gemm<TR_SCALEROW, TR_NONE><<<dim3(16, 1, 1), 256, 0, stream>>>(g0);

  // x2_base = embeds @ pe_w + ph_b (batched, once)
  GemmArgs ge{};
  ge.A = embeds; ge.lda = 1024; ge.B = pe_w; ge.ldb = 1000; ge.K = 1024; ge.ksplit = 1;
  ge.N = 1000; ge.bias = ph_b; ge.C = x2_base; ge.ldc = 1024; ge.partStride = 0;
  k_gemm<TR_NONE, TR_NONE><<<dim3(16, 1, 64), 256, 0, stream>>>(ge);

  // prologue: gh(0) = (h0*m0) @ gru_wh (split-4)
  k_x2gh<<<512, 256, 0, stream>>>(h0, 2048, gwh, mask, ph_w, nullptr, gh_p,
                                  x2_p, 1, 0);

  for (int t = 0; t < 64; t++) {
    float* feat_t = feats + (long)t * 196608;
    const float* hprev = t ? feats + (long)(t - 1) * 196608 : h0;
    int ldh = t ? 3072 : 2048;

    k_gather<<<64, 256, 0, stream>>>(zw, aw, zb, actions + (long)t * 384,
                                     xa_t0, in_g, in_b, mask + t * 64, idxb,
                                     xe, t);
    k_gigemm<<<480, 256, 0, stream>>>(xe, gwi, gi_p);
    k_gates<<<512, 256, 0, stream>>>(gi_p, gh_p, gbi, gbh, hprev, ldh,
                                     mask + t * 64, feat_t, hlast, t);
    k_x2gh<<<512, 256, 0, stream>>>(feat_t, 3072, gwh,
                                    mask + (t + 1 < 64 ? (t + 1) * 64 : 0),
                                    ph_w, x2_base + (long)t * 65536, gh_p,
                                    x2_p, (t < 63) ? 1 : 0, 1);
    k_ppfuse<<<64, 256, 0, stream>>>(x2_p, pp_w, pp_b, po_g, po_b,
                                     posts + (long)t * 65536,
                                     samples + (long)t * 65536, feat_t, zlast,
                                     idxb, t);
  }

  // prior head (batched over all T*B rows)
  GemmArgs gp1{};
  gp1.A = feats; gp1.lda = 3072; gp1.B = prh_w; gp1.ldb = 1000; gp1.K = 2048; gp1.ksplit = 1;
  gp1.N = 1000; gp1.bias = prh_b; gp1.C = xp; gp1.ldc = 1024; gp1.partStride = 0;
  k_gemm<TR_NONE, TR_NONE><<<dim3(16, 1, 64), 256, 0, stream>>>(gp1);
  k_prstat<<<1024, 256, 0, stream>>>(xp, stats_p, 1000);
  GemmArgs gp2{};
  gp2.A = xp; gp2.lda = 1024; gp2.B = prp_w; gp2.ldb = 1024; gp2.K = 1000; gp2.ksplit = 1;
  gp2.N = 1024; gp2.bias = prp_b; gp2.t1s = stats_p; gp2.t1g = pr_g; gp2.t1b = pr_b;
  gp2.C = priors; gp2.ldc = 1024; gp2.partStride = 0;
  k_gemm<TR_LNELU, TR_NONE><<<dim3(16, 1, 64), 256, 0, stream>>>(gp2);
}